// Round 1
// baseline (426.081 us; speedup 1.0000x reference)
//
#include <hip/hip_runtime.h>

#define FP8_MAX 448.0f
#define EPSF 1e-12f

#define BM 128
#define BN 128
#define BK 32

typedef __attribute__((ext_vector_type(8))) _Float16 half8;
typedef __attribute__((ext_vector_type(4))) float floatx4;

__device__ inline void async_copy16(const void* gp, void* lp) {
  __builtin_amdgcn_global_load_lds(
      (const __attribute__((address_space(1))) unsigned int*)gp,
      (__attribute__((address_space(3))) unsigned int*)lp,
      16, 0, 0);
}

// ---------------- absmax reduction: out = max(|in|) as uint bits ----------
__global__ void absmax_kernel(const float* __restrict__ in, int n4,
                              unsigned* __restrict__ out) {
  int tid = blockIdx.x * blockDim.x + threadIdx.x;
  int stride = gridDim.x * blockDim.x;
  const float4* in4 = (const float4*)in;
  float m = 0.f;
  for (int i = tid; i < n4; i += stride) {
    float4 v = in4[i];
    m = fmaxf(m, fmaxf(fmaxf(fabsf(v.x), fabsf(v.y)),
                       fmaxf(fabsf(v.z), fabsf(v.w))));
  }
  // wave-64 shuffle reduce
  for (int off = 32; off > 0; off >>= 1)
    m = fmaxf(m, __shfl_down(m, off, 64));
  __shared__ float smax[4];
  int lane = threadIdx.x & 63, w = threadIdx.x >> 6;
  if (lane == 0) smax[w] = m;
  __syncthreads();
  if (threadIdx.x == 0) {
    float b = fmaxf(fmaxf(smax[0], smax[1]), fmaxf(smax[2], smax[3]));
    atomicMax(out, __float_as_uint(b));  // nonneg float bits: uint-monotonic
  }
}

// ---------------- quantize: fp32 -> fp16 integers in [-448,448] -----------
__global__ void quant_kernel(const float* __restrict__ in,
                             _Float16* __restrict__ out, int n8,
                             const unsigned* __restrict__ amax_bits) {
  const float scale = fmaxf(__uint_as_float(*amax_bits) / FP8_MAX, EPSF);
  int tid = blockIdx.x * blockDim.x + threadIdx.x;
  int stride = gridDim.x * blockDim.x;
  const float4* in4 = (const float4*)in;
  half8* out8 = (half8*)out;
  for (int i = tid; i < n8; i += stride) {
    float4 a = in4[2 * i], b = in4[2 * i + 1];
    half8 h;
    h[0] = (_Float16)rintf(fminf(fmaxf(a.x / scale, -FP8_MAX), FP8_MAX));
    h[1] = (_Float16)rintf(fminf(fmaxf(a.y / scale, -FP8_MAX), FP8_MAX));
    h[2] = (_Float16)rintf(fminf(fmaxf(a.z / scale, -FP8_MAX), FP8_MAX));
    h[3] = (_Float16)rintf(fminf(fmaxf(a.w / scale, -FP8_MAX), FP8_MAX));
    h[4] = (_Float16)rintf(fminf(fmaxf(b.x / scale, -FP8_MAX), FP8_MAX));
    h[5] = (_Float16)rintf(fminf(fmaxf(b.y / scale, -FP8_MAX), FP8_MAX));
    h[6] = (_Float16)rintf(fminf(fmaxf(b.z / scale, -FP8_MAX), FP8_MAX));
    h[7] = (_Float16)rintf(fminf(fmaxf(b.w / scale, -FP8_MAX), FP8_MAX));
    out8[i] = h;
  }
}

// ---------------- NT GEMM: C[m][n] = sum_k A[m][k]*B[n][k], dequant+bias ---
// m97 structure: 128x128 tile, BK=32, 4 waves (2x2), 4x4 16x16 fragments/wave,
// global_load_lds width-16 staging, 2-barrier K-loop.
__global__ void gemm_q_kernel(const _Float16* __restrict__ A,  // [M][K]
                              const _Float16* __restrict__ B,  // [N][K]
                              const float* __restrict__ bias,  // [N]
                              const unsigned* __restrict__ amax,
                              float* __restrict__ C,  // [M][N]
                              int M, int N, int K) {
  __shared__ __align__(16) _Float16 As[BM * BK];
  __shared__ __align__(16) _Float16 Bs[BN * BK];

  const int tid = threadIdx.x;
  const int w = tid >> 6;        // wave 0..3
  const int lane = tid & 63;
  const int wr = w >> 1;         // wave row 0..1
  const int wc = w & 1;          // wave col 0..1
  const int bm = blockIdx.y;
  const int bn = blockIdx.x;

  const _Float16* Ab = A + (size_t)bm * BM * K;
  const _Float16* Bb = B + (size_t)bn * BN * K;

  // per-lane global staging offsets: 16B per lane, 4 lanes per 32-elem row
  const int srow = lane >> 2;       // row within 16-row chunk
  const int scol = (lane & 3) * 8;  // halves

  floatx4 acc[4][4] = {};

  for (int k0 = 0; k0 < K; k0 += BK) {
#pragma unroll
    for (int c = 0; c < 2; ++c) {
      const int chunk = c * 4 + w;  // 0..7, wave-uniform
      async_copy16(Ab + (size_t)(chunk * 16 + srow) * K + k0 + scol,
                   &As[chunk * 16 * BK]);
      async_copy16(Bb + (size_t)(chunk * 16 + srow) * K + k0 + scol,
                   &Bs[chunk * 16 * BK]);
    }
    __syncthreads();  // compiler drains vmcnt before s_barrier

    half8 af[4], bf[4];
#pragma unroll
    for (int i = 0; i < 4; ++i) {
      af[i] = *(const half8*)&As[(wr * 64 + i * 16 + (lane & 15)) * BK +
                                 (lane >> 4) * 8];
      bf[i] = *(const half8*)&Bs[(wc * 64 + i * 16 + (lane & 15)) * BK +
                                 (lane >> 4) * 8];
    }
#pragma unroll
    for (int mi = 0; mi < 4; ++mi)
#pragma unroll
      for (int ni = 0; ni < 4; ++ni)
        acc[mi][ni] = __builtin_amdgcn_mfma_f32_16x16x32_f16(
            af[mi], bf[ni], acc[mi][ni], 0, 0, 0);
    __syncthreads();
  }

  const float sx = fmaxf(__uint_as_float(amax[0]) / FP8_MAX, EPSF);
  const float sw = fmaxf(__uint_as_float(amax[1]) / FP8_MAX, EPSF);
  const float s = sx * sw;

  // C/D layout (verified m89): col = lane&15, row = (lane>>4)*4 + reg
  const int row0 = bm * BM + wr * 64 + (lane >> 4) * 4;
  const int col0 = bn * BN + wc * 64 + (lane & 15);

  float bv[4];
#pragma unroll
  for (int ni = 0; ni < 4; ++ni) bv[ni] = bias[col0 + ni * 16];

#pragma unroll
  for (int mi = 0; mi < 4; ++mi) {
#pragma unroll
    for (int ni = 0; ni < 4; ++ni) {
      const size_t base = (size_t)(row0 + mi * 16) * N + col0 + ni * 16;
#pragma unroll
      for (int r = 0; r < 4; ++r)
        C[base + (size_t)r * N] = acc[mi][ni][r] * s + bv[ni];
    }
  }
}

extern "C" void kernel_launch(void* const* d_in, const int* in_sizes, int n_in,
                              void* d_out, int out_size, void* d_ws,
                              size_t ws_size, hipStream_t stream) {
  const float* x = (const float*)d_in[0];
  const float* wgt = (const float*)d_in[1];
  const float* bias = (const float*)d_in[2];
  float* out = (float*)d_out;

  const int N = in_sizes[2];        // out features (4096)
  const int K = in_sizes[1] / N;    // in features (4096)
  const int M = in_sizes[0] / K;    // rows (8192)

  unsigned* amax = (unsigned*)d_ws;
  _Float16* xq = (_Float16*)((char*)d_ws + 256);
  _Float16* wq =
      (_Float16*)((char*)d_ws + 256 + (size_t)M * K * sizeof(_Float16));

  hipMemsetAsync(d_ws, 0, 8, stream);
  absmax_kernel<<<2048, 256, 0, stream>>>(x, M * K / 4, amax);
  absmax_kernel<<<1024, 256, 0, stream>>>(wgt, N * K / 4, amax + 1);
  quant_kernel<<<2048, 256, 0, stream>>>(x, xq, M * K / 8, amax);
  quant_kernel<<<1024, 256, 0, stream>>>(wgt, wq, N * K / 8, amax + 1);
  gemm_q_kernel<<<dim3(N / BN, M / BM), 256, 0, stream>>>(xq, wq, bias, amax,
                                                          out, M, N, K);
}

// Round 2
// 408.350 us; speedup vs baseline: 1.0434x; 1.0434x over previous
//
#include <hip/hip_runtime.h>

#define FP8_MAX 448.0f
#define EPSF 1e-12f

#define BM 256
#define BN 256
#define BK 64

typedef __attribute__((ext_vector_type(8))) _Float16 half8;
typedef __attribute__((ext_vector_type(4))) float floatx4;

__device__ inline void async_copy16(const void* gp, void* lp) {
  __builtin_amdgcn_global_load_lds(
      (const __attribute__((address_space(1))) unsigned int*)gp,
      (__attribute__((address_space(3))) unsigned int*)lp,
      16, 0, 0);
}

// ---------------- absmax reduction: out = max(|in|) as uint bits ----------
__global__ void absmax_kernel(const float* __restrict__ in, int n4,
                              unsigned* __restrict__ out) {
  int tid = blockIdx.x * blockDim.x + threadIdx.x;
  int stride = gridDim.x * blockDim.x;
  const float4* in4 = (const float4*)in;
  float m = 0.f;
  for (int i = tid; i < n4; i += stride) {
    float4 v = in4[i];
    m = fmaxf(m, fmaxf(fmaxf(fabsf(v.x), fabsf(v.y)),
                       fmaxf(fabsf(v.z), fabsf(v.w))));
  }
  for (int off = 32; off > 0; off >>= 1)
    m = fmaxf(m, __shfl_down(m, off, 64));
  __shared__ float smax[4];
  int lane = threadIdx.x & 63, w = threadIdx.x >> 6;
  if (lane == 0) smax[w] = m;
  __syncthreads();
  if (threadIdx.x == 0) {
    float b = fmaxf(fmaxf(smax[0], smax[1]), fmaxf(smax[2], smax[3]));
    atomicMax(out, __float_as_uint(b));  // nonneg float bits: uint-monotonic
  }
}

// ---------------- quantize: fp32 -> fp16 integers in [-448,448] -----------
__global__ void quant_kernel(const float* __restrict__ in,
                             _Float16* __restrict__ out, int n8,
                             const unsigned* __restrict__ amax_bits) {
  const float scale = fmaxf(__uint_as_float(*amax_bits) / FP8_MAX, EPSF);
  int tid = blockIdx.x * blockDim.x + threadIdx.x;
  int stride = gridDim.x * blockDim.x;
  const float4* in4 = (const float4*)in;
  half8* out8 = (half8*)out;
  for (int i = tid; i < n8; i += stride) {
    float4 a = in4[2 * i], b = in4[2 * i + 1];
    half8 h;
    h[0] = (_Float16)rintf(fminf(fmaxf(a.x / scale, -FP8_MAX), FP8_MAX));
    h[1] = (_Float16)rintf(fminf(fmaxf(a.y / scale, -FP8_MAX), FP8_MAX));
    h[2] = (_Float16)rintf(fminf(fmaxf(a.z / scale, -FP8_MAX), FP8_MAX));
    h[3] = (_Float16)rintf(fminf(fmaxf(a.w / scale, -FP8_MAX), FP8_MAX));
    h[4] = (_Float16)rintf(fminf(fmaxf(b.x / scale, -FP8_MAX), FP8_MAX));
    h[5] = (_Float16)rintf(fminf(fmaxf(b.y / scale, -FP8_MAX), FP8_MAX));
    h[6] = (_Float16)rintf(fminf(fmaxf(b.z / scale, -FP8_MAX), FP8_MAX));
    h[7] = (_Float16)rintf(fminf(fmaxf(b.w / scale, -FP8_MAX), FP8_MAX));
    out8[i] = h;
  }
}

// ---------------- 256x256 8-phase NT GEMM (T1+T2+T3+T4+T5) ----------------
// 8 waves (2M x 4N), per-wave output 128x64, BK=64 (2 k-steps of K=32).
// LDS: 2 dbuf x (A 256x64 + B 256x64) f16 = 128 KiB, 1 block/CU.
// Swizzle: data granule gd lands at LDS granule gd^(row&7) via pre-swizzled
// global source (linear global_load_lds dest) + swizzled ds_read address.
// Stagger: tile t's A-halves staged at t-2.p3, B-halves at t-1.p0/p1;
// boundary s_waitcnt vmcnt(4) leaves only the 2 newest half-tiles in flight.
__global__ __launch_bounds__(512, 2) void gemm8_kernel(
    const _Float16* __restrict__ A,  // [M][K]
    const _Float16* __restrict__ B,  // [N][K]
    const float* __restrict__ bias, const unsigned* __restrict__ amax,
    float* __restrict__ C,  // [M][N]
    int M, int N, int K) {
  __shared__ __align__(16) _Float16 As[2][BM * BK];
  __shared__ __align__(16) _Float16 Bs[2][BN * BK];

  const int tid = threadIdx.x;
  const int w = tid >> 6;   // wave 0..7
  const int lane = tid & 63;
  const int wr = w >> 2;    // wave M-row 0..1  -> A-half wr
  const int wc = w & 3;     // wave N-col 0..3  -> B-half wc>>1

  // XCD-aware block swizzle (gridDim.x divisible by 8)
  const int nwg = gridDim.x;
  const int cpx = nwg >> 3;
  const int swz = (blockIdx.x & 7) * cpx + (blockIdx.x >> 3);
  const int nbn = N / BN;
  const int bm = swz / nbn;
  const int bn = swz % nbn;

  const _Float16* Ab = A + (size_t)bm * BM * K;
  const _Float16* Bb = B + (size_t)bn * BN * K;

  // --- staging geometry: per instruction a wave covers 8 rows x 64 cols.
  // lane l -> LDS row base+ (l>>3), LDS granule l&7; fetches DATA granule
  // (l&7)^((l>>3)&7) so that reader's XOR-swizzle sees linear data.
  const int srow8 = w * 8 + (lane >> 3);                  // 0..63
  const int gd8 = ((lane & 7) ^ ((lane >> 3) & 7)) * 8;   // elems
  const _Float16* Ag = Ab + (size_t)srow8 * K + gd8;
  const _Float16* Bg = Bb + (size_t)srow8 * K + gd8;

  auto stageA = [&](int kt, int h) {  // h in {0,1}: rows h*128..+127
#pragma unroll
    for (int r = 0; r < 2; ++r)
      async_copy16(Ag + (size_t)(h * 128 + r * 64) * K + kt * BK,
                   (void*)&As[kt & 1][(h * 128 + r * 64 + w * 8) * BK]);
  };
  auto stageB = [&](int kt, int h) {
#pragma unroll
    for (int r = 0; r < 2; ++r)
      async_copy16(Bg + (size_t)(h * 128 + r * 64) * K + kt * BK,
                   (void*)&Bs[kt & 1][(h * 128 + r * 64 + w * 8) * BK]);
  };

  // --- ds_read geometry (swizzled): frag row = base16 + (lane&15),
  // granule = kk*4 + (lane>>4), swizzled granule = g ^ (row&7).
  const int lr = lane & 15;
  const int hi = lane >> 4;
  const int aoff = (wr * 128 + lr) * BK;  // elems
  const int boff = (wc * 64 + lr) * BK;
  const int g0 = ((hi) ^ (lr & 7)) * 8;       // kk=0
  const int g1 = ((4 + hi) ^ (lr & 7)) * 8;   // kk=1

  floatx4 acc[8][4] = {};
  const int nt = K / BK;

  // ---- prologue: tile0 fully + tile1 A-halves; keep tile1 A in flight
  stageA(0, 0); stageA(0, 1); stageB(0, 0); stageB(0, 1);
  stageA(1, 0); stageA(1, 1);
  asm volatile("s_waitcnt vmcnt(4)" ::: "memory");
  __builtin_amdgcn_s_barrier();

  for (int t = 0; t < nt; ++t) {
    const int b = t & 1;
    const _Float16* Asb = &As[b][0];
    const _Float16* Bsb = &Bs[b][0];
    half8 a_lo0[4], a_hi0[4], a_lo1[4], a_hi1[4], bf0[4], bf1[4];

    // ================= phase 0: read kk0(A-lo)+kk0(B); MFMA m0-3 kk0
#pragma unroll
    for (int m = 0; m < 4; ++m)
      a_lo0[m] = *(const half8*)&Asb[aoff + m * 16 * BK + g0];
#pragma unroll
    for (int n = 0; n < 4; ++n)
      bf0[n] = *(const half8*)&Bsb[boff + n * 16 * BK + g0];
    if (t + 1 < nt) stageB(t + 1, 0);
    __builtin_amdgcn_s_barrier();
    asm volatile("s_waitcnt lgkmcnt(0)");
    __builtin_amdgcn_s_setprio(1);
#pragma unroll
    for (int m = 0; m < 4; ++m)
#pragma unroll
      for (int n = 0; n < 4; ++n)
        acc[m][n] = __builtin_amdgcn_mfma_f32_16x16x32_f16(
            a_lo0[m], bf0[n], acc[m][n], 0, 0, 0);
    __builtin_amdgcn_s_setprio(0);
    __builtin_amdgcn_s_barrier();

    // ================= phase 1: read kk0(A-hi)+kk1(B); MFMA m4-7 kk0
#pragma unroll
    for (int m = 0; m < 4; ++m)
      a_hi0[m] = *(const half8*)&Asb[aoff + (64 + m * 16) * BK + g0];
#pragma unroll
    for (int n = 0; n < 4; ++n)
      bf1[n] = *(const half8*)&Bsb[boff + n * 16 * BK + g1];
    if (t + 1 < nt) stageB(t + 1, 1);
    __builtin_amdgcn_s_barrier();
    asm volatile("s_waitcnt lgkmcnt(0)");
    __builtin_amdgcn_s_setprio(1);
#pragma unroll
    for (int m = 0; m < 4; ++m)
#pragma unroll
      for (int n = 0; n < 4; ++n)
        acc[4 + m][n] = __builtin_amdgcn_mfma_f32_16x16x32_f16(
            a_hi0[m], bf0[n], acc[4 + m][n], 0, 0, 0);
    __builtin_amdgcn_s_setprio(0);
    __builtin_amdgcn_s_barrier();

    // ================= phase 2: read kk1(A-lo + A-hi); MFMA m0-3 kk1
#pragma unroll
    for (int m = 0; m < 4; ++m)
      a_lo1[m] = *(const half8*)&Asb[aoff + m * 16 * BK + g1];
#pragma unroll
    for (int m = 0; m < 4; ++m)
      a_hi1[m] = *(const half8*)&Asb[aoff + (64 + m * 16) * BK + g1];
    __builtin_amdgcn_s_barrier();
    asm volatile("s_waitcnt lgkmcnt(0)");
    __builtin_amdgcn_s_setprio(1);
#pragma unroll
    for (int m = 0; m < 4; ++m)
#pragma unroll
      for (int n = 0; n < 4; ++n)
        acc[m][n] = __builtin_amdgcn_mfma_f32_16x16x32_f16(
            a_lo1[m], bf1[n], acc[m][n], 0, 0, 0);
    __builtin_amdgcn_s_setprio(0);
    __builtin_amdgcn_s_barrier();

    // ================= phase 3: stage next A into CURRENT buf (reads done);
    // MFMA m4-7 kk1; counted vmcnt at the tile boundary.
    __builtin_amdgcn_sched_barrier(0);  // no reads may sink past this point
    if (t + 2 < nt) { stageA(t + 2, 0); stageA(t + 2, 1); }
    __builtin_amdgcn_s_barrier();
    __builtin_amdgcn_s_setprio(1);
#pragma unroll
    for (int m = 0; m < 4; ++m)
#pragma unroll
      for (int n = 0; n < 4; ++n)
        acc[4 + m][n] = __builtin_amdgcn_mfma_f32_16x16x32_f16(
            a_hi1[m], bf1[n], acc[4 + m][n], 0, 0, 0);
    __builtin_amdgcn_s_setprio(0);
    if (t + 2 < nt) {
      asm volatile("s_waitcnt vmcnt(4)" ::: "memory");
    } else {
      asm volatile("s_waitcnt vmcnt(0)" ::: "memory");
    }
    __builtin_amdgcn_s_barrier();
  }

  // ---- epilogue: dequant + bias, direct stores
  const float sx = fmaxf(__uint_as_float(amax[0]) / FP8_MAX, EPSF);
  const float sw = fmaxf(__uint_as_float(amax[1]) / FP8_MAX, EPSF);
  const float s = sx * sw;

  const int row0 = bm * BM + wr * 128 + hi * 4;  // C/D: col=lane&15,
  const int col0 = bn * BN + wc * 64 + lr;       // row=(lane>>4)*4+reg
  float bv[4];
#pragma unroll
  for (int n = 0; n < 4; ++n) bv[n] = bias[col0 + n * 16];

#pragma unroll
  for (int m = 0; m < 8; ++m) {
#pragma unroll
    for (int n = 0; n < 4; ++n) {
      const size_t base = (size_t)(row0 + m * 16) * N + col0 + n * 16;
#pragma unroll
      for (int r = 0; r < 4; ++r)
        C[base + (size_t)r * N] = acc[m][n][r] * s + bv[n];
    }
  }
}

extern "C" void kernel_launch(void* const* d_in, const int* in_sizes, int n_in,
                              void* d_out, int out_size, void* d_ws,
                              size_t ws_size, hipStream_t stream) {
  const float* x = (const float*)d_in[0];
  const float* wgt = (const float*)d_in[1];
  const float* bias = (const float*)d_in[2];
  float* out = (float*)d_out;

  const int N = in_sizes[2];      // out features (4096)
  const int K = in_sizes[1] / N;  // in features (4096)
  const int M = in_sizes[0] / K;  // rows (8192)

  unsigned* amax = (unsigned*)d_ws;
  _Float16* xq = (_Float16*)((char*)d_ws + 256);
  _Float16* wq =
      (_Float16*)((char*)d_ws + 256 + (size_t)M * K * sizeof(_Float16));

  hipMemsetAsync(d_ws, 0, 8, stream);
  absmax_kernel<<<2048, 256, 0, stream>>>(x, M * K / 4, amax);
  absmax_kernel<<<1024, 256, 0, stream>>>(wgt, N * K / 4, amax + 1);
  quant_kernel<<<2048, 256, 0, stream>>>(x, xq, M * K / 8, amax);
  quant_kernel<<<1024, 256, 0, stream>>>(wgt, wq, N * K / 8, amax + 1);

  gemm8_kernel<<<dim3((M / BM) * (N / BN)), 512, 0, stream>>>(
      xq, wq, bias, amax, out, M, N, K);
}